// Round 13
// baseline (435.689 us; speedup 1.0000x reference)
//
#include <hip/hip_runtime.h>

using short8 = __attribute__((ext_vector_type(8))) short;
using f32x16 = __attribute__((ext_vector_type(16))) float;

#define THR_LOGIT (-1.0986122886681098f)   // ln(1/3): sigmoid(x)>0.25 <=> x>ln(1/3)
#define ZPAGE_OFF 156509184                // zpage byte offset within ws (in2 base)

__device__ __forceinline__ unsigned short f2bf(float f) {
  unsigned u = __float_as_uint(f);
  u = (u + 0x7FFFu + ((u >> 16) & 1u)) >> 16;   // RNE
  return (unsigned short)u;
}

__device__ __forceinline__ void async_copy16(void* lds, const void* g) {
  __builtin_amdgcn_global_load_lds(
      (const __attribute__((address_space(1))) unsigned int*)g,
      (__attribute__((address_space(3))) unsigned int*)lds, 16, 0, 0);
}

// ---------------- prep: weight transposes ----------------
// wt2: [co8(8)][dy(3)][dx(3)][dz(3)][half(2)][l31(32)][8c] bf16 (110592 shorts)
__global__ void __launch_bounds__(256) k_prep(const float* __restrict__ c1w,
    const float* __restrict__ pw1, const float* __restrict__ pw2,
    short* __restrict__ wt2, float* __restrict__ w1t, float* __restrict__ w2t) {
  int i = blockIdx.x * 256 + threadIdx.x;
  if (i < 110592) {
    int j8 = i & 7, l31v = (i >> 3) & 31, halfv = (i >> 8) & 1;
    int q = i >> 9;                      // 0..215 = [co8][dy][dx][dz]
    int dz = q % 3; q /= 3;
    int dx = q % 3; q /= 3;
    int dy = q % 3; int co8 = q / 3;
    int c = co8 * 16 + halfv * 8 + j8;
    int tap = dz * 9 + dy * 3 + dx;
    wt2[i] = (short)f2bf(c1w[l31v * 3456 + c * 27 + tap]);
  } else if (i < 126976) {
    int i2 = i - 110592; int c = i2 >> 7; int j = i2 & 127;
    w1t[i2] = pw1[j * 128 + c];
  } else if (i < 135168) {
    int i3 = i - 126976; int j = i3 >> 6; int d = i3 & 63;
    w2t[i3] = pw2[d * 128 + j];
  }
}

__global__ void k_inv(const int* __restrict__ vidx, int* __restrict__ inv) {
  int t = threadIdx.x;
  for (int k = t; k < 4096; k += 256) inv[k] = -1;
  __syncthreads();
  if (t < 100) inv[vidx[t]] = t;
}

// ---------------- stage: transpose->bf16 [b][z][y][co8(8)][x][16c] (pre-swizzled),
// patch sums, voxel gather (unchanged) ----
__global__ void __launch_bounds__(256) k_stage(const float* __restrict__ src,
    short* __restrict__ in2, float* __restrict__ S4, float* __restrict__ Xmat,
    const int* __restrict__ inv, int vox_row_base) {
  __shared__ float tile[128][65];
  __shared__ int mcnt;
  __shared__ int mx[64];
  __shared__ int mrow[64];
  int bi = blockIdx.x;
  int b = bi >> 8, z = (bi >> 2) & 63, yp = bi & 3;
  int t = threadIdx.x;
  int zp = z >> 4, pz = z & 15;
  int cc = t & 127, xh = t >> 7;
  float part0 = 0.f, part1 = 0.f;

  for (int y0 = 0; y0 < 16; ++y0) {
    int y = yp * 16 + y0;
    __syncthreads();
    if (t == 0) mcnt = 0;
    {
      int x = t & 63, w = t >> 6;
      const float* sp = src + (long)b * 128 * 262144 + (long)z * 4096 + (long)y * 64 + x;
      #pragma unroll 4
      for (int it = 0; it < 32; ++it) {
        int c = it * 4 + w;
        tile[c][x] = sp[(long)c * 262144];
      }
    }
    __syncthreads();
    if (in2 != nullptr) {
      long rowbase = ((long)(b * 64 + z) * 64 + y) * 8192;
      int x = t >> 2, q = t & 3;
      int slot = (q & 1) ^ ((x >> 2) & 1);
      #pragma unroll
      for (int i = 0; i < 4; ++i) {
        int co8 = i * 2 + (q >> 1);
        short8 pk;
        #pragma unroll
        for (int j = 0; j < 8; ++j) pk[j] = (short)f2bf(tile[i * 32 + q * 8 + j][x]);
        *(short8*)(in2 + rowbase + co8 * 1024 + x * 16 + slot * 8) = pk;
      }
    }
    {
      float s0 = 0.f, s1 = 0.f;
      #pragma unroll
      for (int px = 0; px < 16; ++px) s0 += tile[cc][(xh * 2) * 16 + px];
      #pragma unroll
      for (int px = 0; px < 16; ++px) s1 += tile[cc][(xh * 2 + 1) * 16 + px];
      part0 += s0; part1 += s1;
    }
    if (t < 64) {
      int s = inv[pz * 256 + y0 * 16 + (t & 15)];
      if (s >= 0) {
        int idx = atomicAdd(&mcnt, 1);
        mx[idx] = t;
        int n = zp * 16 + yp * 4 + (t >> 4);
        mrow[idx] = vox_row_base + (b * 64 + n) * 100 + s;
      }
    }
    __syncthreads();
    int mc = mcnt;
    for (int i = 0; i < mc; ++i) {
      if (t < 128) Xmat[(long)mrow[i] * 128 + t] = tile[t][mx[i]];
    }
  }
  long sb = ((long)(b * 64 + z) * 4 + yp) * 512;
  S4[sb + cc * 4 + xh * 2 + 0] = part0;
  S4[sb + cc * 4 + xh * 2 + 1] = part1;
}

// ---------------- conv: 2z x 2y waves (4 acc), double-buffered async window ----
// grid 512 (XCD-swizzled): b(2) x zb(16: 4z) x yg(16: 4y). 512 thr = 8 waves (xh,zo,yo).
// Wave outputs (z0+zo*2+{0,1}) x (y0+yo*2+{0,1}) x 32x x 32och.
// Per dx-column: 16 A ds_reads + 9 B loads -> 36 MFMA (0.44 reads/MFMA, B feeds 4).
// Window: 36 rows (6z x 6y) x 2KB = 72KB x 2 buffers + 1KB zero = 145KB -> 1 block/CU,
// 2 waves/SIMD. Stage of pass co8+1 issued async (global_load_lds) before compute of
// co8; single end-of-pass barrier drains vmcnt (R9 pattern + R12 geometry).
__global__ void __launch_bounds__(512, 1) k_conv(const short* __restrict__ in2,
    const short* __restrict__ wt2, const float* __restrict__ c1b,
    const float* __restrict__ c2w, const float* __restrict__ c2b,
    int* __restrict__ counts) {
  extern __shared__ char smem[];
  __shared__ int lcnt[4];
  int bi0 = blockIdx.x;
  int bi = ((bi0 & 7) << 6) | (bi0 >> 3);          // bijective XCD swizzle (512 = 8*64)
  int b = bi >> 8, zb = (bi >> 4) & 15, yg = bi & 15;
  int z0 = zb * 4, y0 = yg * 4;
  int tid = threadIdx.x;
  int lane = tid & 63;
  int l31 = lane & 31, half = lane >> 5;
  int wave = tid >> 6;
  int xh = wave & 1, zo = (wave >> 1) & 1, yo = wave >> 2;

  if (tid < 4) lcnt[tid] = 0;
  if (tid < 64) *(int4*)(smem + 147456 + tid * 16) = int4{0, 0, 0, 0};  // zero row (1KB)
  int zoff = 147456 + lane * 16;

  // staging addresses (loop-invariant): 9 granules/thread; row = zs*6+yl (0..35)
  int gbase[9];
  int gmask[9];
  #pragma unroll
  for (int k = 0; k < 9; ++k) {
    int g = k * 512 + tid;
    int row = g >> 7, pos = g & 127;
    int zz = z0 - 1 + row / 6;
    int yy = y0 - 1 + row % 6;
    bool v = ((unsigned)zz < 64u) && ((unsigned)yy < 64u);
    gbase[k] = v ? (((b * 64 + zz) * 64 + yy) * 16384 + pos * 16)
                 : (ZPAGE_OFF + pos * 16);
    gmask[k] = v ? -1 : 0;
  }
  const char* gsrc = (const char*)in2;

  // A-read lane offsets per dx (zoff-folded for x-OOB via mask trick)
  int xbase = xh * 32 + l31;
  int offA[3];
  int vmA[3];
  #pragma unroll
  for (int d = 0; d < 3; ++d) {
    int xp = xbase + d - 1;
    bool v = (unsigned)xp < 64u;
    int xc = min(max(xp, 0), 63);
    offA[d] = v ? (xc * 32 + ((half ^ ((xc >> 2) & 1)) << 4)) : zoff;
    vmA[d] = v ? -1 : 0;
  }
  int wbase = (zo * 2 * 6 + yo * 2) * 2048;        // wave's window corner (row units)
  const short8* pBbase = (const short8*)wt2 + half * 32 + l31;

  f32x16 acc[2][2] = {};

  // ---- stage pass 0 into buffer 0 ----
  #pragma unroll
  for (int k = 0; k < 9; ++k)
    async_copy16(smem + (k * 512 + tid) * 16, gsrc + gbase[k]);
  __syncthreads();

  for (int co8 = 0; co8 < 8; ++co8) {
    int curoff = (co8 & 1) * 73728;
    // ---- issue async stage of pass co8+1 into the other buffer (hidden) ----
    if (co8 < 7) {
      char* nxt = smem + (73728 - curoff);
      int cadd = (co8 + 1) * 2048;
      #pragma unroll
      for (int k = 0; k < 9; ++k)
        async_copy16(nxt + (k * 512 + tid) * 16, gsrc + gbase[k] + (cadd & gmask[k]));
    }
    // ---- compute: 3 dx columns x {16 A ds_read + 9 B + 36 MFMA} ----
    #pragma unroll
    for (int dx = 0; dx < 3; ++dx) {
      int m = vmA[dx], o = offA[dx];
      short8 A[4][4];
      #pragma unroll
      for (int i = 0; i < 4; ++i)
        #pragma unroll
        for (int j = 0; j < 4; ++j)
          A[i][j] = *(const short8*)(smem +
              (((curoff + wbase) + (i * 6 + j) * 2048) & m) + o);
      __builtin_amdgcn_s_setprio(1);
      #pragma unroll
      for (int dz = 0; dz < 3; ++dz) {
        #pragma unroll
        for (int dy = 0; dy < 3; ++dy) {
          short8 bf = pBbase[((co8 * 9 + dy * 3 + dx) * 3 + dz) * 64];
          acc[0][0] = __builtin_amdgcn_mfma_f32_32x32x16_bf16(A[dz + 0][dy + 0], bf, acc[0][0], 0, 0, 0);
          acc[1][0] = __builtin_amdgcn_mfma_f32_32x32x16_bf16(A[dz + 1][dy + 0], bf, acc[1][0], 0, 0, 0);
          acc[0][1] = __builtin_amdgcn_mfma_f32_32x32x16_bf16(A[dz + 0][dy + 1], bf, acc[0][1], 0, 0, 0);
          acc[1][1] = __builtin_amdgcn_mfma_f32_32x32x16_bf16(A[dz + 1][dy + 1], bf, acc[1][1], 0, 0, 0);
        }
      }
      __builtin_amdgcn_s_setprio(0);
    }
    __syncthreads();   // drains vmcnt -> next buffer ready; all reads of cur done
  }

  // ---- epilogue: relu, 1x1, och-reduce, threshold, patch counts (4 voxel rows) ----
  float b1v = c1b[l31];
  float w2v = c2w[l31];
  float b2v = c2b[0];
  int cnt0 = 0, cnt1 = 0;
  #pragma unroll
  for (int zi = 0; zi < 2; ++zi) {
    #pragma unroll
    for (int yi = 0; yi < 2; ++yi) {
      #pragma unroll
      for (int r = 0; r < 16; ++r) {
        float v = fmaxf(acc[zi][yi][r] + b1v, 0.f) * w2v;
        v += __shfl_xor(v, 1);
        v += __shfl_xor(v, 2);
        v += __shfl_xor(v, 4);
        v += __shfl_xor(v, 8);
        v += __shfl_xor(v, 16);
        int bit = (v + b2v) > THR_LOGIT;
        if (r < 8) cnt0 += bit; else cnt1 += bit; // xp-local = (r>=8)
      }
    }
  }
  if (l31 == 0) {                                  // lanes 0 and 32: disjoint row sets
    atomicAdd(&lcnt[xh * 2 + 0], cnt0);
    atomicAdd(&lcnt[xh * 2 + 1], cnt1);
  }
  __syncthreads();
  if (tid < 4) {
    int n = (zb >> 2) * 16 + (yg >> 2) * 4 + tid;
    atomicAdd(&counts[b * 64 + n], lcnt[tid]);
  }
}

// ---------------- reduce S4 -> X vec rows (deterministic) ----------------
__global__ void __launch_bounds__(256) k_vecreduce(const float* __restrict__ S4a,
    const float* __restrict__ S4p, float* __restrict__ Xmat) {
  int g = blockIdx.x * 256 + threadIdx.x;   // 32768
  int ten = g >> 14, rem = g & 16383;
  int b = rem >> 13, n = (rem >> 7) & 63, c = rem & 127;
  int zp = n >> 4, yp = (n >> 2) & 3, xp = n & 3;
  const float* S = ten ? S4p : S4a;
  float s = 0.f;
  #pragma unroll
  for (int k = 0; k < 16; ++k)
    s += S[((long)(b * 64 + zp * 16 + k) * 4 + yp) * 512 + c * 4 + xp];
  Xmat[(long)(ten * 128 + b * 64 + n) * 128 + c] = s * (1.f / 4096.f);
}

// ---------------- projector MLP + normalize ----------------
__global__ void __launch_bounds__(256) k_proj(const float* __restrict__ Xmat,
    const float* __restrict__ w1t, const float* __restrict__ pb1,
    const float* __restrict__ w2t, const float* __restrict__ pb2,
    float* __restrict__ P) {
  __shared__ float xsT[128][20];
  __shared__ float hsT[128][20];
  __shared__ float os[16][68];
  int bi = blockIdx.x;
  long row0 = (long)bi * 16;
  int t = threadIdx.x;
  {
    int r = t >> 4, c0 = (t & 15) * 8;
    const float* xp = Xmat + (row0 + r) * 128 + c0;
    #pragma unroll
    for (int k = 0; k < 8; ++k) xsT[c0 + k][r] = xp[k];
  }
  __syncthreads();
  {
    int j = t & 127, rh = t >> 7;
    float hacc[8];
    float bb = pb1[j];
    #pragma unroll
    for (int r8 = 0; r8 < 8; ++r8) hacc[r8] = bb;
    for (int c = 0; c < 128; ++c) {
      float w = w1t[c * 128 + j];
      float4 xlo = *(const float4*)&xsT[c][rh * 8];
      float4 xhi = *(const float4*)&xsT[c][rh * 8 + 4];
      hacc[0] += xlo.x * w; hacc[1] += xlo.y * w; hacc[2] += xlo.z * w; hacc[3] += xlo.w * w;
      hacc[4] += xhi.x * w; hacc[5] += xhi.y * w; hacc[6] += xhi.z * w; hacc[7] += xhi.w * w;
    }
    #pragma unroll
    for (int r8 = 0; r8 < 8; ++r8) hsT[j][rh * 8 + r8] = fmaxf(hacc[r8], 0.f);
  }
  __syncthreads();
  {
    int d = t & 63, rq = t >> 6;
    float oacc[4];
    float bb = pb2[d];
    #pragma unroll
    for (int r4 = 0; r4 < 4; ++r4) oacc[r4] = bb;
    for (int j = 0; j < 128; ++j) {
      float w = w2t[j * 64 + d];
      float4 hv = *(const float4*)&hsT[j][rq * 4];
      oacc[0] += hv.x * w; oacc[1] += hv.y * w; oacc[2] += hv.z * w; oacc[3] += hv.w * w;
    }
    #pragma unroll
    for (int r4 = 0; r4 < 4; ++r4) os[rq * 4 + r4][d] = oacc[r4];
  }
  __syncthreads();
  {
    int r = t >> 4, dg = t & 15;
    float4 v = *(const float4*)&os[r][dg * 4];
    float ss = v.x * v.x + v.y * v.y + v.z * v.z + v.w * v.w;
    ss += __shfl_xor(ss, 1); ss += __shfl_xor(ss, 2);
    ss += __shfl_xor(ss, 4); ss += __shfl_xor(ss, 8);
    float sc = 1.f / fmaxf(sqrtf(ss), 1e-12f);
    float4 o; o.x = v.x * sc; o.y = v.y * sc; o.z = v.z * sc; o.w = v.w * sc;
    *(float4*)&P[(row0 + r) * 64 + dg * 4] = o;
  }
}

// ---------------- sim + logsumexp per (b,n) ----------------
__global__ void __launch_bounds__(128) k_sim(const float* __restrict__ P,
                                             float* __restrict__ vloss) {
  __shared__ float ps[100][68];
  __shared__ float red[128];
  int bn = blockIdx.x;
  int t = threadIdx.x;
  long pbase = (long)(13056 + bn * 100) * 64;
  for (int i = t; i < 1600; i += 128) {
    int r = i >> 4, dg = i & 15;
    *(float4*)&ps[r][dg * 4] = *(const float4*)&P[pbase + r * 64 + dg * 4];
  }
  float4 areg[16];
  long abase = (long)(256 + bn * 100) * 64;
  if (t < 100) {
    #pragma unroll
    for (int j = 0; j < 16; ++j) areg[j] = *(const float4*)&P[abase + (long)t * 64 + j * 4];
  }
  __syncthreads();
  float res = 0.f;
  if (t < 100) {
    float m = -1e30f, sum = 0.f, diag = 0.f;
    for (int t2 = 0; t2 < 100; ++t2) {
      float d = 0.f;
      #pragma unroll
      for (int j = 0; j < 16; ++j) {
        float4 pv = *(const float4*)&ps[t2][j * 4];
        d += areg[j].x * pv.x + areg[j].y * pv.y + areg[j].z * pv.z + areg[j].w * pv.w;
      }
      float sim = d * 10.f;
      if (t2 == t) diag = sim;
      float nm = fmaxf(m, sim);
      sum = sum * __expf(m - nm) + __expf(sim - nm);
      m = nm;
    }
    res = m + logf(sum) - diag;
  }
  red[t] = res;
  __syncthreads();
  if (t == 0) {
    float s = 0.f;
    for (int i = 0; i < 100; ++i) s += red[i];
    vloss[bn] = s * 0.01f;
  }
}

// ---------------- final weighted reduction ----------------
__global__ void __launch_bounds__(128) k_final(const float* __restrict__ P,
    const float* __restrict__ vloss, const int* __restrict__ counts,
    const float* __restrict__ lw, float* __restrict__ out) {
  int t = threadIdx.x;
  int lane = t & 63;
  float pterm = 0.f, vterm = 0.f; int vcnt = 0;
  {
    int c = counts[t];
    bool maskv = c >= 2458;   // ratio > 0.6
    bool maskp = c <= 1638;   // ratio < 0.4
    float d = 0.f;
    for (int k = 0; k < 64; ++k) d += P[t * 64 + k] * P[(128 + t) * 64 + k];
    if (maskp) { pterm = -d * 10.f; vcnt += 1; }
    if (maskv) { vterm = vloss[t];  vcnt += 1; }
  }
  for (int m = 1; m < 64; m <<= 1) {
    pterm += __shfl_xor(pterm, m);
    vterm += __shfl_xor(vterm, m);
    vcnt  += __shfl_xor(vcnt, m);
  }
  __shared__ float sp[2], sv[2]; __shared__ int sc[2];
  if (lane == 0) { sp[t >> 6] = pterm; sv[t >> 6] = vterm; sc[t >> 6] = vcnt; }
  __syncthreads();
  if (t == 0) {
    float psum = sp[0] + sp[1], vsum = sv[0] + sv[1];
    int vc = sc[0] + sc[1];
    float total = lw[0] * psum + lw[1] * vsum;
    out[0] = (vc > 0) ? total / (float)vc : 0.f;
  }
}

// ---------------- launch ----------------
extern "C" void kernel_launch(void* const* d_in, const int* in_sizes, int n_in,
                              void* d_out, int out_size, void* d_ws, size_t ws_size,
                              hipStream_t stream) {
  const float* anchor   = (const float*)d_in[0];
  const float* positive = (const float*)d_in[1];
  const float* c1w = (const float*)d_in[2];
  const float* c1b = (const float*)d_in[3];
  const float* c2w = (const float*)d_in[4];
  const float* c2b = (const float*)d_in[5];
  const float* pw1 = (const float*)d_in[6];
  const float* pb1 = (const float*)d_in[7];
  const float* pw2 = (const float*)d_in[8];
  const float* pb2 = (const float*)d_in[9];
  const float* lw  = (const float*)d_in[10];
  const int*   vidx = (const int*)d_in[11];

  char* ws = (char*)d_ws;
  short* in2   = (short*)(ws + 0);                 // 134,217,728
  float* S4a   = (float*)(ws + 134217728);         // 1,048,576
  float* S4p   = (float*)(ws + 135266304);         // 1,048,576
  float* X     = (float*)(ws + 136314880);         // 13,238,272
  float* P     = (float*)(ws + 149553152);         // 6,619,136
  short* wt2   = (short*)(ws + 156172288);         // 221,184
  float* w1t   = (float*)(ws + 156393472);         // 65,536
  float* w2t   = (float*)(ws + 156459008);         // 32,768
  int*   inv   = (int*)  (ws + 156491776);         // 16,384
  int*   counts= (int*)  (ws + 156508160);         // 512
  float* vloss = (float*)(ws + 156508672);         // 512
  short* zpage = (short*)(ws + ZPAGE_OFF);         // 16,384 (zero page, offset 156509184)

  hipFuncSetAttribute(reinterpret_cast<const void*>(k_conv),
                      hipFuncAttributeMaxDynamicSharedMemorySize, 148480);

  hipMemsetAsync(counts, 0, 128 * sizeof(int), stream);
  hipMemsetAsync(zpage, 0, 16384, stream);
  k_prep<<<528, 256, 0, stream>>>(c1w, pw1, pw2, wt2, w1t, w2t);
  k_inv<<<1, 256, 0, stream>>>(vidx, inv);
  k_stage<<<512, 256, 0, stream>>>(anchor,   in2,     S4a, X, inv, 256);
  k_stage<<<512, 256, 0, stream>>>(positive, nullptr, S4p, X, inv, 13056);
  k_conv<<<512, 512, 148480, stream>>>(in2, wt2, c1b, c2w, c2b, counts);
  k_vecreduce<<<128, 256, 0, stream>>>(S4a, S4p, X);
  k_proj<<<1616, 256, 0, stream>>>(X, w1t, pb1, w2t, pb2, P);
  k_sim<<<128, 128, 0, stream>>>(P, vloss);
  k_final<<<1, 128, 0, stream>>>(P, vloss, counts, lw, (float*)d_out);
}

// Round 14
// 415.236 us; speedup vs baseline: 1.0493x; 1.0493x over previous
//
#include <hip/hip_runtime.h>

using short8 = __attribute__((ext_vector_type(8))) short;
using f32x16 = __attribute__((ext_vector_type(16))) float;

#define THR_LOGIT (-1.0986122886681098f)   // ln(1/3): sigmoid(x)>0.25 <=> x>ln(1/3)
#define ZPAGE_OFF 156509184                // zpage byte offset within ws (in2 base)

__device__ __forceinline__ unsigned short f2bf(float f) {
  unsigned u = __float_as_uint(f);
  u = (u + 0x7FFFu + ((u >> 16) & 1u)) >> 16;   // RNE
  return (unsigned short)u;
}

__device__ __forceinline__ void async_copy16(void* lds, const void* g) {
  __builtin_amdgcn_global_load_lds(
      (const __attribute__((address_space(1))) unsigned int*)g,
      (__attribute__((address_space(3))) unsigned int*)lds, 16, 0, 0);
}

// ---------------- prep: weight transposes ----------------
// wt2: [co8(8)][dy(3)][dx(3)][dz(3)][half(2)][l31(32)][8c] bf16 (110592 shorts)
__global__ void __launch_bounds__(256) k_prep(const float* __restrict__ c1w,
    const float* __restrict__ pw1, const float* __restrict__ pw2,
    short* __restrict__ wt2, float* __restrict__ w1t, float* __restrict__ w2t) {
  int i = blockIdx.x * 256 + threadIdx.x;
  if (i < 110592) {
    int j8 = i & 7, l31v = (i >> 3) & 31, halfv = (i >> 8) & 1;
    int q = i >> 9;                      // 0..215 = [co8][dy][dx][dz]
    int dz = q % 3; q /= 3;
    int dx = q % 3; q /= 3;
    int dy = q % 3; int co8 = q / 3;
    int c = co8 * 16 + halfv * 8 + j8;
    int tap = dz * 9 + dy * 3 + dx;
    wt2[i] = (short)f2bf(c1w[l31v * 3456 + c * 27 + tap]);
  } else if (i < 126976) {
    int i2 = i - 110592; int c = i2 >> 7; int j = i2 & 127;
    w1t[i2] = pw1[j * 128 + c];
  } else if (i < 135168) {
    int i3 = i - 126976; int j = i3 >> 6; int d = i3 & 63;
    w2t[i3] = pw2[d * 128 + j];
  }
}

__global__ void k_inv(const int* __restrict__ vidx, int* __restrict__ inv) {
  int t = threadIdx.x;
  for (int k = t; k < 4096; k += 256) inv[k] = -1;
  __syncthreads();
  if (t < 100) inv[vidx[t]] = t;
}

// ---------------- stage: float4 global loads, transpose->bf16, patch sums, gather ----
__global__ void __launch_bounds__(256) k_stage(const float* __restrict__ src,
    short* __restrict__ in2, float* __restrict__ S4, float* __restrict__ Xmat,
    const int* __restrict__ inv, int vox_row_base) {
  __shared__ float tile[128][65];
  __shared__ int mcnt;
  __shared__ int mx[64];
  __shared__ int mrow[64];
  int bi = blockIdx.x;
  int b = bi >> 8, z = (bi >> 2) & 63, yp = bi & 3;
  int t = threadIdx.x;
  int zp = z >> 4, pz = z & 15;
  int cc = t & 127, xh = t >> 7;
  float part0 = 0.f, part1 = 0.f;

  for (int y0 = 0; y0 < 16; ++y0) {
    int y = yp * 16 + y0;
    __syncthreads();
    if (t == 0) mcnt = 0;
    // float4 loads: thread t covers rows c = s*16 + (t>>4), x-quad (t&15)*4  (16B/lane)
    {
      int xq = (t & 15) * 4, w = t >> 4;
      const float* sp = src + (long)b * 128 * 262144 + (long)z * 4096 + (long)y * 64 + xq;
      #pragma unroll
      for (int s = 0; s < 8; ++s) {
        int c = s * 16 + w;
        float4 v = *(const float4*)(sp + (long)c * 262144);
        tile[c][xq + 0] = v.x;
        tile[c][xq + 1] = v.y;
        tile[c][xq + 2] = v.z;
        tile[c][xq + 3] = v.w;
      }
    }
    __syncthreads();
    if (in2 != nullptr) {
      long rowbase = ((long)(b * 64 + z) * 64 + y) * 8192;
      int x = t >> 2, q = t & 3;
      int slot = (q & 1) ^ ((x >> 2) & 1);
      #pragma unroll
      for (int i = 0; i < 4; ++i) {
        int co8 = i * 2 + (q >> 1);
        short8 pk;
        #pragma unroll
        for (int j = 0; j < 8; ++j) pk[j] = (short)f2bf(tile[i * 32 + q * 8 + j][x]);
        *(short8*)(in2 + rowbase + co8 * 1024 + x * 16 + slot * 8) = pk;
      }
    }
    {
      float s0 = 0.f, s1 = 0.f;
      #pragma unroll
      for (int px = 0; px < 16; ++px) s0 += tile[cc][(xh * 2) * 16 + px];
      #pragma unroll
      for (int px = 0; px < 16; ++px) s1 += tile[cc][(xh * 2 + 1) * 16 + px];
      part0 += s0; part1 += s1;
    }
    if (t < 64) {
      int s = inv[pz * 256 + y0 * 16 + (t & 15)];
      if (s >= 0) {
        int idx = atomicAdd(&mcnt, 1);
        mx[idx] = t;
        int n = zp * 16 + yp * 4 + (t >> 4);
        mrow[idx] = vox_row_base + (b * 64 + n) * 100 + s;
      }
    }
    __syncthreads();
    int mc = mcnt;
    for (int i = 0; i < mc; ++i) {
      if (t < 128) Xmat[(long)mrow[i] * 128 + t] = tile[t][mx[i]];
    }
  }
  long sb = ((long)(b * 64 + z) * 4 + yp) * 512;
  S4[sb + cc * 4 + xh * 2 + 0] = part0;
  S4[sb + cc * 4 + xh * 2 + 1] = part1;
}

// ---------------- conv: EXACT R12 (best: 164us, VGPR 116, MfmaUtil 29%) ----------------
// grid 1024 (XCD-swizzled): b(2) x zb(32: 2z) x yg(16: 4y). 256 thr = 4 waves (xh, yo).
// Wave outputs (z0,z0+1) x (y0+yo*2+{0,1}) x 32x x 32och.
// Per dx-column per pass: 16 A ds_reads + 9 B loads -> 36 MFMA (each B feeds 4 MFMAs).
// Window: 24 rows (4z x 6y) x 2KB = 48KB + 1KB zero. launch_bounds(256,2), 2 blocks/CU.
__global__ void __launch_bounds__(256, 2) k_conv(const short* __restrict__ in2,
    const short* __restrict__ wt2, const float* __restrict__ c1b,
    const float* __restrict__ c2w, const float* __restrict__ c2b,
    int* __restrict__ counts) {
  extern __shared__ char smem[];
  __shared__ int lcnt[4];
  int bi0 = blockIdx.x;
  int bi = ((bi0 & 7) << 7) | (bi0 >> 3);          // bijective XCD swizzle (1024 = 8*128)
  int b = bi >> 9, zb = (bi >> 4) & 31, yg = bi & 15;
  int z0 = zb * 2, y0 = yg * 4;
  int tid = threadIdx.x;
  int lane = tid & 63;
  int l31 = lane & 31, half = lane >> 5;
  int wave = tid >> 6;
  int xh = wave & 1, yo = wave >> 1;               // yo 0..1

  if (tid < 4) lcnt[tid] = 0;
  *(int*)(smem + 49152 + tid * 4) = 0;             // zero row (1 KB)
  int zoff = 49152 + lane * 16;

  // staging addresses (loop-invariant): 12 granules/thread; row 0..23, pos 0..127
  int gbase[12];
  int gmask[12];
  #pragma unroll
  for (int k = 0; k < 12; ++k) {
    int g = k * 256 + tid;
    int row = g >> 7, pos = g & 127;
    int zz = z0 - 1 + row / 6;
    int yy = y0 - 1 + row % 6;
    bool v = ((unsigned)zz < 64u) && ((unsigned)yy < 64u);
    gbase[k] = v ? (((b * 64 + zz) * 64 + yy) * 16384 + pos * 16)
                 : (ZPAGE_OFF + pos * 16);
    gmask[k] = v ? -1 : 0;
  }
  const char* gsrc = (const char*)in2;

  // A-read lane offsets per dx (zoff-folded for x-OOB)
  int xbase = xh * 32 + l31;
  int offA[3];
  int vmA[3];
  #pragma unroll
  for (int d = 0; d < 3; ++d) {
    int xp = xbase + d - 1;
    bool v = (unsigned)xp < 64u;
    int xc = min(max(xp, 0), 63);
    offA[d] = v ? (xc * 32 + ((half ^ ((xc >> 2) & 1)) << 4)) : zoff;
    vmA[d] = v ? -1 : 0;
  }
  int ybase = yo * 4096;                           // yo*2 rows of 2KB
  const short8* pBbase = (const short8*)wt2 + half * 32 + l31;

  f32x16 acc[2][2] = {};

  // stage pass 0 via async global->LDS
  #pragma unroll
  for (int k = 0; k < 12; ++k)
    async_copy16(smem + (k * 256 + tid) * 16, gsrc + gbase[k]);
  __syncthreads();

  for (int co8 = 0; co8 < 8; ++co8) {
    // ---- compute: 3 dx columns x {16 A ds_read + 9 B + 36 MFMA} ----
    #pragma unroll
    for (int dx = 0; dx < 3; ++dx) {
      int m = vmA[dx], o = offA[dx];
      short8 A[4][4];
      #pragma unroll
      for (int zs = 0; zs < 4; ++zs)
        #pragma unroll
        for (int yr = 0; yr < 4; ++yr)
          A[zs][yr] = *(const short8*)(smem +
              (((zs * 12288 + yr * 2048) + ybase) & m) + o);
      __builtin_amdgcn_s_setprio(1);
      #pragma unroll
      for (int dz = 0; dz < 3; ++dz) {
        #pragma unroll
        for (int dy = 0; dy < 3; ++dy) {
          short8 bf = pBbase[((co8 * 9 + dy * 3 + dx) * 3 + dz) * 64];
          acc[0][0] = __builtin_amdgcn_mfma_f32_32x32x16_bf16(A[dz + 0][dy + 0], bf, acc[0][0], 0, 0, 0);
          acc[1][0] = __builtin_amdgcn_mfma_f32_32x32x16_bf16(A[dz + 1][dy + 0], bf, acc[1][0], 0, 0, 0);
          acc[0][1] = __builtin_amdgcn_mfma_f32_32x32x16_bf16(A[dz + 0][dy + 1], bf, acc[0][1], 0, 0, 0);
          acc[1][1] = __builtin_amdgcn_mfma_f32_32x32x16_bf16(A[dz + 1][dy + 1], bf, acc[1][1], 0, 0, 0);
        }
      }
      __builtin_amdgcn_s_setprio(0);
    }
    __syncthreads();                               // all reads of window done
    if (co8 < 7) {
      int cadd = (co8 + 1) * 2048;
      #pragma unroll
      for (int k = 0; k < 12; ++k)
        async_copy16(smem + (k * 256 + tid) * 16,
                     gsrc + gbase[k] + (cadd & gmask[k]));
      __syncthreads();                             // drains vmcnt -> window ready
    }
  }

  // ---- epilogue: relu, 1x1, och-reduce, threshold, patch counts (4 voxel rows) ----
  float b1v = c1b[l31];
  float w2v = c2w[l31];
  float b2v = c2b[0];
  int cnt0 = 0, cnt1 = 0;
  #pragma unroll
  for (int zi = 0; zi < 2; ++zi) {
    #pragma unroll
    for (int yi = 0; yi < 2; ++yi) {
      #pragma unroll
      for (int r = 0; r < 16; ++r) {
        float v = fmaxf(acc[zi][yi][r] + b1v, 0.f) * w2v;
        v += __shfl_xor(v, 1);
        v += __shfl_xor(v, 2);
        v += __shfl_xor(v, 4);
        v += __shfl_xor(v, 8);
        v += __shfl_xor(v, 16);
        int bit = (v + b2v) > THR_LOGIT;
        if (r < 8) cnt0 += bit; else cnt1 += bit; // xp-local = (row>=16) = (r>=8)
      }
    }
  }
  if (l31 == 0) {                                  // lanes 0 and 32: disjoint row sets
    atomicAdd(&lcnt[xh * 2 + 0], cnt0);
    atomicAdd(&lcnt[xh * 2 + 1], cnt1);
  }
  __syncthreads();
  if (tid < 4) {
    int n = (zb >> 3) * 16 + (yg >> 2) * 4 + tid;
    atomicAdd(&counts[b * 64 + n], lcnt[tid]);
  }
}

// ---------------- reduce S4 -> X vec rows (deterministic) ----------------
__global__ void __launch_bounds__(256) k_vecreduce(const float* __restrict__ S4a,
    const float* __restrict__ S4p, float* __restrict__ Xmat) {
  int g = blockIdx.x * 256 + threadIdx.x;   // 32768
  int ten = g >> 14, rem = g & 16383;
  int b = rem >> 13, n = (rem >> 7) & 63, c = rem & 127;
  int zp = n >> 4, yp = (n >> 2) & 3, xp = n & 3;
  const float* S = ten ? S4p : S4a;
  float s = 0.f;
  #pragma unroll
  for (int k = 0; k < 16; ++k)
    s += S[((long)(b * 64 + zp * 16 + k) * 4 + yp) * 512 + c * 4 + xp];
  Xmat[(long)(ten * 128 + b * 64 + n) * 128 + c] = s * (1.f / 4096.f);
}

// ---------------- projector MLP + normalize ----------------
__global__ void __launch_bounds__(256) k_proj(const float* __restrict__ Xmat,
    const float* __restrict__ w1t, const float* __restrict__ pb1,
    const float* __restrict__ w2t, const float* __restrict__ pb2,
    float* __restrict__ P) {
  __shared__ float xsT[128][20];
  __shared__ float hsT[128][20];
  __shared__ float os[16][68];
  int bi = blockIdx.x;
  long row0 = (long)bi * 16;
  int t = threadIdx.x;
  {
    int r = t >> 4, c0 = (t & 15) * 8;
    const float* xp = Xmat + (row0 + r) * 128 + c0;
    #pragma unroll
    for (int k = 0; k < 8; ++k) xsT[c0 + k][r] = xp[k];
  }
  __syncthreads();
  {
    int j = t & 127, rh = t >> 7;
    float hacc[8];
    float bb = pb1[j];
    #pragma unroll
    for (int r8 = 0; r8 < 8; ++r8) hacc[r8] = bb;
    for (int c = 0; c < 128; ++c) {
      float w = w1t[c * 128 + j];
      float4 xlo = *(const float4*)&xsT[c][rh * 8];
      float4 xhi = *(const float4*)&xsT[c][rh * 8 + 4];
      hacc[0] += xlo.x * w; hacc[1] += xlo.y * w; hacc[2] += xlo.z * w; hacc[3] += xlo.w * w;
      hacc[4] += xhi.x * w; hacc[5] += xhi.y * w; hacc[6] += xhi.z * w; hacc[7] += xhi.w * w;
    }
    #pragma unroll
    for (int r8 = 0; r8 < 8; ++r8) hsT[j][rh * 8 + r8] = fmaxf(hacc[r8], 0.f);
  }
  __syncthreads();
  {
    int d = t & 63, rq = t >> 6;
    float oacc[4];
    float bb = pb2[d];
    #pragma unroll
    for (int r4 = 0; r4 < 4; ++r4) oacc[r4] = bb;
    for (int j = 0; j < 128; ++j) {
      float w = w2t[j * 64 + d];
      float4 hv = *(const float4*)&hsT[j][rq * 4];
      oacc[0] += hv.x * w; oacc[1] += hv.y * w; oacc[2] += hv.z * w; oacc[3] += hv.w * w;
    }
    #pragma unroll
    for (int r4 = 0; r4 < 4; ++r4) os[rq * 4 + r4][d] = oacc[r4];
  }
  __syncthreads();
  {
    int r = t >> 4, dg = t & 15;
    float4 v = *(const float4*)&os[r][dg * 4];
    float ss = v.x * v.x + v.y * v.y + v.z * v.z + v.w * v.w;
    ss += __shfl_xor(ss, 1); ss += __shfl_xor(ss, 2);
    ss += __shfl_xor(ss, 4); ss += __shfl_xor(ss, 8);
    float sc = 1.f / fmaxf(sqrtf(ss), 1e-12f);
    float4 o; o.x = v.x * sc; o.y = v.y * sc; o.z = v.z * sc; o.w = v.w * sc;
    *(float4*)&P[(row0 + r) * 64 + dg * 4] = o;
  }
}

// ---------------- sim + logsumexp per (b,n) ----------------
__global__ void __launch_bounds__(128) k_sim(const float* __restrict__ P,
                                             float* __restrict__ vloss) {
  __shared__ float ps[100][68];
  __shared__ float red[128];
  int bn = blockIdx.x;
  int t = threadIdx.x;
  long pbase = (long)(13056 + bn * 100) * 64;
  for (int i = t; i < 1600; i += 128) {
    int r = i >> 4, dg = i & 15;
    *(float4*)&ps[r][dg * 4] = *(const float4*)&P[pbase + r * 64 + dg * 4];
  }
  float4 areg[16];
  long abase = (long)(256 + bn * 100) * 64;
  if (t < 100) {
    #pragma unroll
    for (int j = 0; j < 16; ++j) areg[j] = *(const float4*)&P[abase + (long)t * 64 + j * 4];
  }
  __syncthreads();
  float res = 0.f;
  if (t < 100) {
    float m = -1e30f, sum = 0.f, diag = 0.f;
    for (int t2 = 0; t2 < 100; ++t2) {
      float d = 0.f;
      #pragma unroll
      for (int j = 0; j < 16; ++j) {
        float4 pv = *(const float4*)&ps[t2][j * 4];
        d += areg[j].x * pv.x + areg[j].y * pv.y + areg[j].z * pv.z + areg[j].w * pv.w;
      }
      float sim = d * 10.f;
      if (t2 == t) diag = sim;
      float nm = fmaxf(m, sim);
      sum = sum * __expf(m - nm) + __expf(sim - nm);
      m = nm;
    }
    res = m + logf(sum) - diag;
  }
  red[t] = res;
  __syncthreads();
  if (t == 0) {
    float s = 0.f;
    for (int i = 0; i < 100; ++i) s += red[i];
    vloss[bn] = s * 0.01f;
  }
}

// ---------------- final weighted reduction ----------------
__global__ void __launch_bounds__(128) k_final(const float* __restrict__ P,
    const float* __restrict__ vloss, const int* __restrict__ counts,
    const float* __restrict__ lw, float* __restrict__ out) {
  int t = threadIdx.x;
  int lane = t & 63;
  float pterm = 0.f, vterm = 0.f; int vcnt = 0;
  {
    int c = counts[t];
    bool maskv = c >= 2458;   // ratio > 0.6
    bool maskp = c <= 1638;   // ratio < 0.4
    float d = 0.f;
    for (int k = 0; k < 64; ++k) d += P[t * 64 + k] * P[(128 + t) * 64 + k];
    if (maskp) { pterm = -d * 10.f; vcnt += 1; }
    if (maskv) { vterm = vloss[t];  vcnt += 1; }
  }
  for (int m = 1; m < 64; m <<= 1) {
    pterm += __shfl_xor(pterm, m);
    vterm += __shfl_xor(vterm, m);
    vcnt  += __shfl_xor(vcnt, m);
  }
  __shared__ float sp[2], sv[2]; __shared__ int sc[2];
  if (lane == 0) { sp[t >> 6] = pterm; sv[t >> 6] = vterm; sc[t >> 6] = vcnt; }
  __syncthreads();
  if (t == 0) {
    float psum = sp[0] + sp[1], vsum = sv[0] + sv[1];
    int vc = sc[0] + sc[1];
    float total = lw[0] * psum + lw[1] * vsum;
    out[0] = (vc > 0) ? total / (float)vc : 0.f;
  }
}

// ---------------- launch ----------------
extern "C" void kernel_launch(void* const* d_in, const int* in_sizes, int n_in,
                              void* d_out, int out_size, void* d_ws, size_t ws_size,
                              hipStream_t stream) {
  const float* anchor   = (const float*)d_in[0];
  const float* positive = (const float*)d_in[1];
  const float* c1w = (const float*)d_in[2];
  const float* c1b = (const float*)d_in[3];
  const float* c2w = (const float*)d_in[4];
  const float* c2b = (const float*)d_in[5];
  const float* pw1 = (const float*)d_in[6];
  const float* pb1 = (const float*)d_in[7];
  const float* pw2 = (const float*)d_in[8];
  const float* pb2 = (const float*)d_in[9];
  const float* lw  = (const float*)d_in[10];
  const int*   vidx = (const int*)d_in[11];

  char* ws = (char*)d_ws;
  short* in2   = (short*)(ws + 0);                 // 134,217,728
  float* S4a   = (float*)(ws + 134217728);         // 1,048,576
  float* S4p   = (float*)(ws + 135266304);         // 1,048,576
  float* X     = (float*)(ws + 136314880);         // 13,238,272
  float* P     = (float*)(ws + 149553152);         // 6,619,136
  short* wt2   = (short*)(ws + 156172288);         // 221,184
  float* w1t   = (float*)(ws + 156393472);         // 65,536
  float* w2t   = (float*)(ws + 156459008);         // 32,768
  int*   inv   = (int*)  (ws + 156491776);         // 16,384
  int*   counts= (int*)  (ws + 156508160);         // 512
  float* vloss = (float*)(ws + 156508672);         // 512
  short* zpage = (short*)(ws + ZPAGE_OFF);         // 16,384 (zero page, offset 156509184)

  hipFuncSetAttribute(reinterpret_cast<const void*>(k_conv),
                      hipFuncAttributeMaxDynamicSharedMemorySize, 50176);

  hipMemsetAsync(counts, 0, 128 * sizeof(int), stream);
  hipMemsetAsync(zpage, 0, 16384, stream);
  k_prep<<<528, 256, 0, stream>>>(c1w, pw1, pw2, wt2, w1t, w2t);
  k_inv<<<1, 256, 0, stream>>>(vidx, inv);
  k_stage<<<512, 256, 0, stream>>>(anchor,   in2,     S4a, X, inv, 256);
  k_stage<<<512, 256, 0, stream>>>(positive, nullptr, S4p, X, inv, 13056);
  k_conv<<<1024, 256, 50176, stream>>>(in2, wt2, c1b, c2w, c2b, counts);
  k_vecreduce<<<128, 256, 0, stream>>>(S4a, S4p, X);
  k_proj<<<1616, 256, 0, stream>>>(X, w1t, pb1, w2t, pb2, P);
  k_sim<<<128, 128, 0, stream>>>(P, vloss);
  k_final<<<1, 128, 0, stream>>>(P, vloss, counts, lw, (float*)d_out);
}

// Round 15
// 386.787 us; speedup vs baseline: 1.1264x; 1.0736x over previous
//
#include <hip/hip_runtime.h>

using short8 = __attribute__((ext_vector_type(8))) short;
using f32x16 = __attribute__((ext_vector_type(16))) float;

#define THR_LOGIT (-1.0986122886681098f)   // ln(1/3): sigmoid(x)>0.25 <=> x>ln(1/3)
#define ZPAGE_OFF 156509184                // zpage byte offset within ws (in2 base)

__device__ __forceinline__ unsigned short f2bf(float f) {
  unsigned u = __float_as_uint(f);
  u = (u + 0x7FFFu + ((u >> 16) & 1u)) >> 16;   // RNE
  return (unsigned short)u;
}

__device__ __forceinline__ void async_copy16(void* lds, const void* g) {
  __builtin_amdgcn_global_load_lds(
      (const __attribute__((address_space(1))) unsigned int*)g,
      (__attribute__((address_space(3))) unsigned int*)lds, 16, 0, 0);
}

// ---------------- prep: weight transposes ----------------
// wt2: [co8(8)][dy(3)][dx(3)][dz(3)][half(2)][l31(32)][8c] bf16 (110592 shorts)
__global__ void __launch_bounds__(256) k_prep(const float* __restrict__ c1w,
    const float* __restrict__ pw1, const float* __restrict__ pw2,
    short* __restrict__ wt2, float* __restrict__ w1t, float* __restrict__ w2t) {
  int i = blockIdx.x * 256 + threadIdx.x;
  if (i < 110592) {
    int j8 = i & 7, l31v = (i >> 3) & 31, halfv = (i >> 8) & 1;
    int q = i >> 9;                      // 0..215 = [co8][dy][dx][dz]
    int dz = q % 3; q /= 3;
    int dx = q % 3; q /= 3;
    int dy = q % 3; int co8 = q / 3;
    int c = co8 * 16 + halfv * 8 + j8;
    int tap = dz * 9 + dy * 3 + dx;
    wt2[i] = (short)f2bf(c1w[l31v * 3456 + c * 27 + tap]);
  } else if (i < 126976) {
    int i2 = i - 110592; int c = i2 >> 7; int j = i2 & 127;
    w1t[i2] = pw1[j * 128 + c];
  } else if (i < 135168) {
    int i3 = i - 126976; int j = i3 >> 6; int d = i3 & 63;
    w2t[i3] = pw2[d * 128 + j];
  }
}

__global__ void k_inv(const int* __restrict__ vidx, int* __restrict__ inv) {
  int t = threadIdx.x;
  for (int k = t; k < 4096; k += 256) inv[k] = -1;
  __syncthreads();
  if (t < 100) inv[vidx[t]] = t;
}

// ---------------- stage body (float4 loads; in2 write optional) ----------------
__device__ __forceinline__ void stage_body(float (*tile)[65], int* mcnt_p, int* mx,
    int* mrow, int bi, int t, const float* __restrict__ src, short* __restrict__ in2,
    float* __restrict__ S4, float* __restrict__ Xmat, const int* __restrict__ inv,
    int vox_row_base) {
  int b = bi >> 8, z = (bi >> 2) & 63, yp = bi & 3;
  int zp = z >> 4, pz = z & 15;
  int cc = t & 127, xh = t >> 7;
  float part0 = 0.f, part1 = 0.f;

  for (int y0 = 0; y0 < 16; ++y0) {
    int y = yp * 16 + y0;
    __syncthreads();
    if (t == 0) *mcnt_p = 0;
    {
      int xq = (t & 15) * 4, w = t >> 4;
      const float* sp = src + (long)b * 128 * 262144 + (long)z * 4096 + (long)y * 64 + xq;
      #pragma unroll
      for (int s = 0; s < 8; ++s) {
        int c = s * 16 + w;
        float4 v = *(const float4*)(sp + (long)c * 262144);
        tile[c][xq + 0] = v.x;
        tile[c][xq + 1] = v.y;
        tile[c][xq + 2] = v.z;
        tile[c][xq + 3] = v.w;
      }
    }
    __syncthreads();
    if (in2 != nullptr) {
      long rowbase = ((long)(b * 64 + z) * 64 + y) * 8192;
      int x = t >> 2, q = t & 3;
      int slot = (q & 1) ^ ((x >> 2) & 1);
      #pragma unroll
      for (int i = 0; i < 4; ++i) {
        int co8 = i * 2 + (q >> 1);
        short8 pk;
        #pragma unroll
        for (int j = 0; j < 8; ++j) pk[j] = (short)f2bf(tile[i * 32 + q * 8 + j][x]);
        *(short8*)(in2 + rowbase + co8 * 1024 + x * 16 + slot * 8) = pk;
      }
    }
    {
      float s0 = 0.f, s1 = 0.f;
      #pragma unroll
      for (int px = 0; px < 16; ++px) s0 += tile[cc][(xh * 2) * 16 + px];
      #pragma unroll
      for (int px = 0; px < 16; ++px) s1 += tile[cc][(xh * 2 + 1) * 16 + px];
      part0 += s0; part1 += s1;
    }
    if (t < 64) {
      int s = inv[pz * 256 + y0 * 16 + (t & 15)];
      if (s >= 0) {
        int idx = atomicAdd(mcnt_p, 1);
        mx[idx] = t;
        int n = zp * 16 + yp * 4 + (t >> 4);
        mrow[idx] = vox_row_base + (b * 64 + n) * 100 + s;
      }
    }
    __syncthreads();
    int mc = *mcnt_p;
    for (int i = 0; i < mc; ++i) {
      if (t < 128) Xmat[(long)mrow[i] * 128 + t] = tile[t][mx[i]];
    }
  }
  long sb = ((long)(b * 64 + z) * 4 + yp) * 512;
  S4[sb + cc * 4 + xh * 2 + 0] = part0;
  S4[sb + cc * 4 + xh * 2 + 1] = part1;
}

// ---------------- stage (anchor): standalone ----------------
__global__ void __launch_bounds__(256) k_stage(const float* __restrict__ src,
    short* __restrict__ in2, float* __restrict__ S4, float* __restrict__ Xmat,
    const int* __restrict__ inv, int vox_row_base) {
  __shared__ float tile[128][65];
  __shared__ int mcnt;
  __shared__ int mx[64];
  __shared__ int mrow[64];
  stage_body(tile, &mcnt, mx, mrow, blockIdx.x, threadIdx.x,
             src, in2, S4, Xmat, inv, vox_row_base);
}

// ---------------- fused: conv (R12-best) + positive stage, role-interleaved ----------
// 1536 blocks: bid%3<2 -> conv block ci=2*(bid/3)+(bid%3) in 0..1023; bid%3==2 ->
// positive-stage block si=bid/3 in 0..511. 3 blocks/CU (50.7KB LDS) => each CU hosts
// a conv+stage mix; stage HBM traffic fills conv's latency bubbles.
__global__ void __launch_bounds__(256, 2) k_fused(const short* __restrict__ in2,
    const short* __restrict__ wt2, const float* __restrict__ c1b,
    const float* __restrict__ c2w, const float* __restrict__ c2b,
    int* __restrict__ counts,
    const float* __restrict__ positive, float* __restrict__ S4p,
    float* __restrict__ Xmat, const int* __restrict__ inv) {
  extern __shared__ char smem[];
  __shared__ int lcnt[4];
  __shared__ int mx[64];
  __shared__ int mrow[64];
  int bid = blockIdx.x;
  int role = bid % 3;
  int tid = threadIdx.x;

  if (role == 2) {
    // ---------------- positive-stage role ----------------
    stage_body((float(*)[65])smem, &lcnt[0], mx, mrow, bid / 3, tid,
               positive, nullptr, S4p, Xmat, inv, 13056);
    return;
  }

  // ---------------- conv role (EXACT R12 body) ----------------
  int bi0 = (bid / 3) * 2 + role;                  // 0..1023
  int bi = ((bi0 & 7) << 7) | (bi0 >> 3);          // bijective XCD swizzle (1024 = 8*128)
  int b = bi >> 9, zb = (bi >> 4) & 31, yg = bi & 15;
  int z0 = zb * 2, y0 = yg * 4;
  int lane = tid & 63;
  int l31 = lane & 31, half = lane >> 5;
  int wave = tid >> 6;
  int xh = wave & 1, yo = wave >> 1;               // yo 0..1

  if (tid < 4) lcnt[tid] = 0;
  *(int*)(smem + 49152 + tid * 4) = 0;             // zero row (1 KB)
  int zoff = 49152 + lane * 16;

  int gbase[12];
  int gmask[12];
  #pragma unroll
  for (int k = 0; k < 12; ++k) {
    int g = k * 256 + tid;
    int row = g >> 7, pos = g & 127;
    int zz = z0 - 1 + row / 6;
    int yy = y0 - 1 + row % 6;
    bool v = ((unsigned)zz < 64u) && ((unsigned)yy < 64u);
    gbase[k] = v ? (((b * 64 + zz) * 64 + yy) * 16384 + pos * 16)
                 : (ZPAGE_OFF + pos * 16);
    gmask[k] = v ? -1 : 0;
  }
  const char* gsrc = (const char*)in2;

  int xbase = xh * 32 + l31;
  int offA[3];
  int vmA[3];
  #pragma unroll
  for (int d = 0; d < 3; ++d) {
    int xp = xbase + d - 1;
    bool v = (unsigned)xp < 64u;
    int xc = min(max(xp, 0), 63);
    offA[d] = v ? (xc * 32 + ((half ^ ((xc >> 2) & 1)) << 4)) : zoff;
    vmA[d] = v ? -1 : 0;
  }
  int ybase = yo * 4096;                           // yo*2 rows of 2KB
  const short8* pBbase = (const short8*)wt2 + half * 32 + l31;

  f32x16 acc[2][2] = {};

  #pragma unroll
  for (int k = 0; k < 12; ++k)
    async_copy16(smem + (k * 256 + tid) * 16, gsrc + gbase[k]);
  __syncthreads();

  for (int co8 = 0; co8 < 8; ++co8) {
    #pragma unroll
    for (int dx = 0; dx < 3; ++dx) {
      int m = vmA[dx], o = offA[dx];
      short8 A[4][4];
      #pragma unroll
      for (int zs = 0; zs < 4; ++zs)
        #pragma unroll
        for (int yr = 0; yr < 4; ++yr)
          A[zs][yr] = *(const short8*)(smem +
              (((zs * 12288 + yr * 2048) + ybase) & m) + o);
      __builtin_amdgcn_s_setprio(1);
      #pragma unroll
      for (int dz = 0; dz < 3; ++dz) {
        #pragma unroll
        for (int dy = 0; dy < 3; ++dy) {
          short8 bf = pBbase[((co8 * 9 + dy * 3 + dx) * 3 + dz) * 64];
          acc[0][0] = __builtin_amdgcn_mfma_f32_32x32x16_bf16(A[dz + 0][dy + 0], bf, acc[0][0], 0, 0, 0);
          acc[1][0] = __builtin_amdgcn_mfma_f32_32x32x16_bf16(A[dz + 1][dy + 0], bf, acc[1][0], 0, 0, 0);
          acc[0][1] = __builtin_amdgcn_mfma_f32_32x32x16_bf16(A[dz + 0][dy + 1], bf, acc[0][1], 0, 0, 0);
          acc[1][1] = __builtin_amdgcn_mfma_f32_32x32x16_bf16(A[dz + 1][dy + 1], bf, acc[1][1], 0, 0, 0);
        }
      }
      __builtin_amdgcn_s_setprio(0);
    }
    __syncthreads();                               // all reads of window done
    if (co8 < 7) {
      int cadd = (co8 + 1) * 2048;
      #pragma unroll
      for (int k = 0; k < 12; ++k)
        async_copy16(smem + (k * 256 + tid) * 16,
                     gsrc + gbase[k] + (cadd & gmask[k]));
      __syncthreads();                             // drains vmcnt -> window ready
    }
  }

  float b1v = c1b[l31];
  float w2v = c2w[l31];
  float b2v = c2b[0];
  int cnt0 = 0, cnt1 = 0;
  #pragma unroll
  for (int zi = 0; zi < 2; ++zi) {
    #pragma unroll
    for (int yi = 0; yi < 2; ++yi) {
      #pragma unroll
      for (int r = 0; r < 16; ++r) {
        float v = fmaxf(acc[zi][yi][r] + b1v, 0.f) * w2v;
        v += __shfl_xor(v, 1);
        v += __shfl_xor(v, 2);
        v += __shfl_xor(v, 4);
        v += __shfl_xor(v, 8);
        v += __shfl_xor(v, 16);
        int bit = (v + b2v) > THR_LOGIT;
        if (r < 8) cnt0 += bit; else cnt1 += bit; // xp-local = (row>=16) = (r>=8)
      }
    }
  }
  if (l31 == 0) {                                  // lanes 0 and 32: disjoint row sets
    atomicAdd(&lcnt[xh * 2 + 0], cnt0);
    atomicAdd(&lcnt[xh * 2 + 1], cnt1);
  }
  __syncthreads();
  if (tid < 4) {
    int n = (zb >> 3) * 16 + (yg >> 2) * 4 + tid;
    atomicAdd(&counts[b * 64 + n], lcnt[tid]);
  }
}

// ---------------- reduce S4 -> X vec rows (deterministic) ----------------
__global__ void __launch_bounds__(256) k_vecreduce(const float* __restrict__ S4a,
    const float* __restrict__ S4p, float* __restrict__ Xmat) {
  int g = blockIdx.x * 256 + threadIdx.x;   // 32768
  int ten = g >> 14, rem = g & 16383;
  int b = rem >> 13, n = (rem >> 7) & 63, c = rem & 127;
  int zp = n >> 4, yp = (n >> 2) & 3, xp = n & 3;
  const float* S = ten ? S4p : S4a;
  float s = 0.f;
  #pragma unroll
  for (int k = 0; k < 16; ++k)
    s += S[((long)(b * 64 + zp * 16 + k) * 4 + yp) * 512 + c * 4 + xp];
  Xmat[(long)(ten * 128 + b * 64 + n) * 128 + c] = s * (1.f / 4096.f);
}

// ---------------- projector MLP + normalize ----------------
__global__ void __launch_bounds__(256) k_proj(const float* __restrict__ Xmat,
    const float* __restrict__ w1t, const float* __restrict__ pb1,
    const float* __restrict__ w2t, const float* __restrict__ pb2,
    float* __restrict__ P) {
  __shared__ float xsT[128][20];
  __shared__ float hsT[128][20];
  __shared__ float os[16][68];
  int bi = blockIdx.x;
  long row0 = (long)bi * 16;
  int t = threadIdx.x;
  {
    int r = t >> 4, c0 = (t & 15) * 8;
    const float* xp = Xmat + (row0 + r) * 128 + c0;
    #pragma unroll
    for (int k = 0; k < 8; ++k) xsT[c0 + k][r] = xp[k];
  }
  __syncthreads();
  {
    int j = t & 127, rh = t >> 7;
    float hacc[8];
    float bb = pb1[j];
    #pragma unroll
    for (int r8 = 0; r8 < 8; ++r8) hacc[r8] = bb;
    for (int c = 0; c < 128; ++c) {
      float w = w1t[c * 128 + j];
      float4 xlo = *(const float4*)&xsT[c][rh * 8];
      float4 xhi = *(const float4*)&xsT[c][rh * 8 + 4];
      hacc[0] += xlo.x * w; hacc[1] += xlo.y * w; hacc[2] += xlo.z * w; hacc[3] += xlo.w * w;
      hacc[4] += xhi.x * w; hacc[5] += xhi.y * w; hacc[6] += xhi.z * w; hacc[7] += xhi.w * w;
    }
    #pragma unroll
    for (int r8 = 0; r8 < 8; ++r8) hsT[j][rh * 8 + r8] = fmaxf(hacc[r8], 0.f);
  }
  __syncthreads();
  {
    int d = t & 63, rq = t >> 6;
    float oacc[4];
    float bb = pb2[d];
    #pragma unroll
    for (int r4 = 0; r4 < 4; ++r4) oacc[r4] = bb;
    for (int j = 0; j < 128; ++j) {
      float w = w2t[j * 64 + d];
      float4 hv = *(const float4*)&hsT[j][rq * 4];
      oacc[0] += hv.x * w; oacc[1] += hv.y * w; oacc[2] += hv.z * w; oacc[3] += hv.w * w;
    }
    #pragma unroll
    for (int r4 = 0; r4 < 4; ++r4) os[rq * 4 + r4][d] = oacc[r4];
  }
  __syncthreads();
  {
    int r = t >> 4, dg = t & 15;
    float4 v = *(const float4*)&os[r][dg * 4];
    float ss = v.x * v.x + v.y * v.y + v.z * v.z + v.w * v.w;
    ss += __shfl_xor(ss, 1); ss += __shfl_xor(ss, 2);
    ss += __shfl_xor(ss, 4); ss += __shfl_xor(ss, 8);
    float sc = 1.f / fmaxf(sqrtf(ss), 1e-12f);
    float4 o; o.x = v.x * sc; o.y = v.y * sc; o.z = v.z * sc; o.w = v.w * sc;
    *(float4*)&P[(row0 + r) * 64 + dg * 4] = o;
  }
}

// ---------------- sim + logsumexp per (b,n) ----------------
__global__ void __launch_bounds__(128) k_sim(const float* __restrict__ P,
                                             float* __restrict__ vloss) {
  __shared__ float ps[100][68];
  __shared__ float red[128];
  int bn = blockIdx.x;
  int t = threadIdx.x;
  long pbase = (long)(13056 + bn * 100) * 64;
  for (int i = t; i < 1600; i += 128) {
    int r = i >> 4, dg = i & 15;
    *(float4*)&ps[r][dg * 4] = *(const float4*)&P[pbase + r * 64 + dg * 4];
  }
  float4 areg[16];
  long abase = (long)(256 + bn * 100) * 64;
  if (t < 100) {
    #pragma unroll
    for (int j = 0; j < 16; ++j) areg[j] = *(const float4*)&P[abase + (long)t * 64 + j * 4];
  }
  __syncthreads();
  float res = 0.f;
  if (t < 100) {
    float m = -1e30f, sum = 0.f, diag = 0.f;
    for (int t2 = 0; t2 < 100; ++t2) {
      float d = 0.f;
      #pragma unroll
      for (int j = 0; j < 16; ++j) {
        float4 pv = *(const float4*)&ps[t2][j * 4];
        d += areg[j].x * pv.x + areg[j].y * pv.y + areg[j].z * pv.z + areg[j].w * pv.w;
      }
      float sim = d * 10.f;
      if (t2 == t) diag = sim;
      float nm = fmaxf(m, sim);
      sum = sum * __expf(m - nm) + __expf(sim - nm);
      m = nm;
    }
    res = m + logf(sum) - diag;
  }
  red[t] = res;
  __syncthreads();
  if (t == 0) {
    float s = 0.f;
    for (int i = 0; i < 100; ++i) s += red[i];
    vloss[bn] = s * 0.01f;
  }
}

// ---------------- final weighted reduction ----------------
__global__ void __launch_bounds__(128) k_final(const float* __restrict__ P,
    const float* __restrict__ vloss, const int* __restrict__ counts,
    const float* __restrict__ lw, float* __restrict__ out) {
  int t = threadIdx.x;
  int lane = t & 63;
  float pterm = 0.f, vterm = 0.f; int vcnt = 0;
  {
    int c = counts[t];
    bool maskv = c >= 2458;   // ratio > 0.6
    bool maskp = c <= 1638;   // ratio < 0.4
    float d = 0.f;
    for (int k = 0; k < 64; ++k) d += P[t * 64 + k] * P[(128 + t) * 64 + k];
    if (maskp) { pterm = -d * 10.f; vcnt += 1; }
    if (maskv) { vterm = vloss[t];  vcnt += 1; }
  }
  for (int m = 1; m < 64; m <<= 1) {
    pterm += __shfl_xor(pterm, m);
    vterm += __shfl_xor(vterm, m);
    vcnt  += __shfl_xor(vcnt, m);
  }
  __shared__ float sp[2], sv[2]; __shared__ int sc[2];
  if (lane == 0) { sp[t >> 6] = pterm; sv[t >> 6] = vterm; sc[t >> 6] = vcnt; }
  __syncthreads();
  if (t == 0) {
    float psum = sp[0] + sp[1], vsum = sv[0] + sv[1];
    int vc = sc[0] + sc[1];
    float total = lw[0] * psum + lw[1] * vsum;
    out[0] = (vc > 0) ? total / (float)vc : 0.f;
  }
}

// ---------------- launch ----------------
extern "C" void kernel_launch(void* const* d_in, const int* in_sizes, int n_in,
                              void* d_out, int out_size, void* d_ws, size_t ws_size,
                              hipStream_t stream) {
  const float* anchor   = (const float*)d_in[0];
  const float* positive = (const float*)d_in[1];
  const float* c1w = (const float*)d_in[2];
  const float* c1b = (const float*)d_in[3];
  const float* c2w = (const float*)d_in[4];
  const float* c2b = (const float*)d_in[5];
  const float* pw1 = (const float*)d_in[6];
  const float* pb1 = (const float*)d_in[7];
  const float* pw2 = (const float*)d_in[8];
  const float* pb2 = (const float*)d_in[9];
  const float* lw  = (const float*)d_in[10];
  const int*   vidx = (const int*)d_in[11];

  char* ws = (char*)d_ws;
  short* in2   = (short*)(ws + 0);                 // 134,217,728
  float* S4a   = (float*)(ws + 134217728);         // 1,048,576
  float* S4p   = (float*)(ws + 135266304);         // 1,048,576
  float* X     = (float*)(ws + 136314880);         // 13,238,272
  float* P     = (float*)(ws + 149553152);         // 6,619,136
  short* wt2   = (short*)(ws + 156172288);         // 221,184
  float* w1t   = (float*)(ws + 156393472);         // 65,536
  float* w2t   = (float*)(ws + 156459008);         // 32,768
  int*   inv   = (int*)  (ws + 156491776);         // 16,384
  int*   counts= (int*)  (ws + 156508160);         // 512
  float* vloss = (float*)(ws + 156508672);         // 512
  short* zpage = (short*)(ws + ZPAGE_OFF);         // 16,384 (zero page, offset 156509184)

  hipFuncSetAttribute(reinterpret_cast<const void*>(k_fused),
                      hipFuncAttributeMaxDynamicSharedMemorySize, 50176);

  hipMemsetAsync(counts, 0, 128 * sizeof(int), stream);
  hipMemsetAsync(zpage, 0, 16384, stream);
  k_prep<<<528, 256, 0, stream>>>(c1w, pw1, pw2, wt2, w1t, w2t);
  k_inv<<<1, 256, 0, stream>>>(vidx, inv);
  k_stage<<<512, 256, 0, stream>>>(anchor, in2, S4a, X, inv, 256);
  k_fused<<<1536, 256, 50176, stream>>>(in2, wt2, c1b, c2w, c2b, counts,
                                        positive, S4p, X, inv);
  k_vecreduce<<<128, 256, 0, stream>>>(S4a, S4p, X);
  k_proj<<<1616, 256, 0, stream>>>(X, w1t, pb1, w2t, pb2, P);
  k_sim<<<128, 128, 0, stream>>>(P, vloss);
  k_final<<<1, 128, 0, stream>>>(P, vloss, counts, lw, (float*)d_out);
}

// Round 16
// 374.575 us; speedup vs baseline: 1.1632x; 1.0326x over previous
//
#include <hip/hip_runtime.h>

using short8 = __attribute__((ext_vector_type(8))) short;
using f32x16 = __attribute__((ext_vector_type(16))) float;

#define THR_LOGIT (-1.0986122886681098f)   // ln(1/3): sigmoid(x)>0.25 <=> x>ln(1/3)
#define ZPAGE_OFF 156509184                // zpage byte offset within ws (in2 base)

__device__ __forceinline__ unsigned short f2bf(float f) {
  unsigned u = __float_as_uint(f);
  u = (u + 0x7FFFu + ((u >> 16) & 1u)) >> 16;   // RNE
  return (unsigned short)u;
}

__device__ __forceinline__ void async_copy16(void* lds, const void* g) {
  __builtin_amdgcn_global_load_lds(
      (const __attribute__((address_space(1))) unsigned int*)g,
      (__attribute__((address_space(3))) unsigned int*)lds, 16, 0, 0);
}

// ---------------- prep: weight transposes ----------------
// wt2: [co8(8)][dy(3)][dx(3)][dz(3)][half(2)][l31(32)][8c] bf16 (110592 shorts)
__global__ void __launch_bounds__(256) k_prep(const float* __restrict__ c1w,
    const float* __restrict__ pw1, const float* __restrict__ pw2,
    short* __restrict__ wt2, float* __restrict__ w1t, float* __restrict__ w2t) {
  int i = blockIdx.x * 256 + threadIdx.x;
  if (i < 110592) {
    int j8 = i & 7, l31v = (i >> 3) & 31, halfv = (i >> 8) & 1;
    int q = i >> 9;                      // 0..215 = [co8][dy][dx][dz]
    int dz = q % 3; q /= 3;
    int dx = q % 3; q /= 3;
    int dy = q % 3; int co8 = q / 3;
    int c = co8 * 16 + halfv * 8 + j8;
    int tap = dz * 9 + dy * 3 + dx;
    wt2[i] = (short)f2bf(c1w[l31v * 3456 + c * 27 + tap]);
  } else if (i < 126976) {
    int i2 = i - 110592; int c = i2 >> 7; int j = i2 & 127;
    w1t[i2] = pw1[j * 128 + c];
  } else if (i < 135168) {
    int i3 = i - 126976; int j = i3 >> 6; int d = i3 & 63;
    w2t[i3] = pw2[d * 128 + j];
  }
}

__global__ void k_inv(const int* __restrict__ vidx, int* __restrict__ inv) {
  int t = threadIdx.x;
  for (int k = t; k < 4096; k += 256) inv[k] = -1;
  __syncthreads();
  if (t < 100) inv[vidx[t]] = t;
}

// ---------------- stage body (float4 loads; in2 write optional) ----------------
__device__ __forceinline__ void stage_body(float (*tile)[65], int* mcnt_p, int* mx,
    int* mrow, int bi, int t, const float* __restrict__ src, short* __restrict__ in2,
    float* __restrict__ S4, float* __restrict__ Xmat, const int* __restrict__ inv,
    int vox_row_base) {
  int b = bi >> 8, z = (bi >> 2) & 63, yp = bi & 3;
  int zp = z >> 4, pz = z & 15;
  int cc = t & 127, xh = t >> 7;
  float part0 = 0.f, part1 = 0.f;

  for (int y0 = 0; y0 < 16; ++y0) {
    int y = yp * 16 + y0;
    __syncthreads();
    if (t == 0) *mcnt_p = 0;
    {
      int xq = (t & 15) * 4, w = t >> 4;
      const float* sp = src + (long)b * 128 * 262144 + (long)z * 4096 + (long)y * 64 + xq;
      #pragma unroll
      for (int s = 0; s < 8; ++s) {
        int c = s * 16 + w;
        float4 v = *(const float4*)(sp + (long)c * 262144);
        tile[c][xq + 0] = v.x;
        tile[c][xq + 1] = v.y;
        tile[c][xq + 2] = v.z;
        tile[c][xq + 3] = v.w;
      }
    }
    __syncthreads();
    if (in2 != nullptr) {
      long rowbase = ((long)(b * 64 + z) * 64 + y) * 8192;
      int x = t >> 2, q = t & 3;
      int slot = (q & 1) ^ ((x >> 2) & 1);
      #pragma unroll
      for (int i = 0; i < 4; ++i) {
        int co8 = i * 2 + (q >> 1);
        short8 pk;
        #pragma unroll
        for (int j = 0; j < 8; ++j) pk[j] = (short)f2bf(tile[i * 32 + q * 8 + j][x]);
        *(short8*)(in2 + rowbase + co8 * 1024 + x * 16 + slot * 8) = pk;
      }
    }
    {
      float s0 = 0.f, s1 = 0.f;
      #pragma unroll
      for (int px = 0; px < 16; ++px) s0 += tile[cc][(xh * 2) * 16 + px];
      #pragma unroll
      for (int px = 0; px < 16; ++px) s1 += tile[cc][(xh * 2 + 1) * 16 + px];
      part0 += s0; part1 += s1;
    }
    if (t < 64) {
      int s = inv[pz * 256 + y0 * 16 + (t & 15)];
      if (s >= 0) {
        int idx = atomicAdd(mcnt_p, 1);
        mx[idx] = t;
        int n = zp * 16 + yp * 4 + (t >> 4);
        mrow[idx] = vox_row_base + (b * 64 + n) * 100 + s;
      }
    }
    __syncthreads();
    int mc = *mcnt_p;
    for (int i = 0; i < mc; ++i) {
      if (t < 128) Xmat[(long)mrow[i] * 128 + t] = tile[t][mx[i]];
    }
  }
  long sb = ((long)(b * 64 + z) * 4 + yp) * 512;
  S4[sb + cc * 4 + xh * 2 + 0] = part0;
  S4[sb + cc * 4 + xh * 2 + 1] = part1;
}

// ---------------- stage (anchor): standalone ----------------
__global__ void __launch_bounds__(256) k_stage(const float* __restrict__ src,
    short* __restrict__ in2, float* __restrict__ S4, float* __restrict__ Xmat,
    const int* __restrict__ inv, int vox_row_base) {
  __shared__ float tile[128][65];
  __shared__ int mcnt;
  __shared__ int mx[64];
  __shared__ int mrow[64];
  stage_body(tile, &mcnt, mx, mrow, blockIdx.x, threadIdx.x,
             src, in2, S4, Xmat, inv, vox_row_base);
}

// ---------------- fused: conv (R12-best) + positive stage, role-interleaved ----------
// 1536 blocks: bid%3<2 -> conv block ci=2*(bid/3)+(bid%3); bid%3==2 -> positive-stage
// block si=bid/3. LDS = exactly 48KB (zero row eliminated; x-OOB via data cndmask)
// => 3 blocks/CU robustly; each CU hosts 2 conv + 1 stage, stage rides conv's idle HBM.
__global__ void __launch_bounds__(256, 2) k_fused(const short* __restrict__ in2,
    const short* __restrict__ wt2, const float* __restrict__ c1b,
    const float* __restrict__ c2w, const float* __restrict__ c2b,
    int* __restrict__ counts,
    const float* __restrict__ positive, float* __restrict__ S4p,
    float* __restrict__ Xmat, const int* __restrict__ inv) {
  extern __shared__ char smem[];
  __shared__ int lcnt[4];
  __shared__ int mx[64];
  __shared__ int mrow[64];
  int bid = blockIdx.x;
  int role = bid % 3;
  int tid = threadIdx.x;

  if (role == 2) {
    // ---------------- positive-stage role ----------------
    stage_body((float(*)[65])smem, &lcnt[0], mx, mrow, bid / 3, tid,
               positive, nullptr, S4p, Xmat, inv, 13056);
    return;
  }

  // ---------------- conv role (R12 body; x-OOB via data cndmask) ----------------
  int bi0 = (bid / 3) * 2 + role;                  // 0..1023
  int bi = ((bi0 & 7) << 7) | (bi0 >> 3);          // bijective XCD swizzle (1024 = 8*128)
  int b = bi >> 9, zb = (bi >> 4) & 31, yg = bi & 15;
  int z0 = zb * 2, y0 = yg * 4;
  int lane = tid & 63;
  int l31 = lane & 31, half = lane >> 5;
  int wave = tid >> 6;
  int xh = wave & 1, yo = wave >> 1;               // yo 0..1
  const short8 zer = {};

  if (tid < 4) lcnt[tid] = 0;

  int gbase[12];
  int gmask[12];
  #pragma unroll
  for (int k = 0; k < 12; ++k) {
    int g = k * 256 + tid;
    int row = g >> 7, pos = g & 127;
    int zz = z0 - 1 + row / 6;
    int yy = y0 - 1 + row % 6;
    bool v = ((unsigned)zz < 64u) && ((unsigned)yy < 64u);
    gbase[k] = v ? (((b * 64 + zz) * 64 + yy) * 16384 + pos * 16)
                 : (ZPAGE_OFF + pos * 16);
    gmask[k] = v ? -1 : 0;
  }
  const char* gsrc = (const char*)in2;

  int xbase = xh * 32 + l31;
  int offA[3];
  bool vA[3];
  #pragma unroll
  for (int d = 0; d < 3; ++d) {
    int xp = xbase + d - 1;
    vA[d] = (unsigned)xp < 64u;
    int xc = min(max(xp, 0), 63);
    offA[d] = xc * 32 + ((half ^ ((xc >> 2) & 1)) << 4);
  }
  int ybase = yo * 4096;                           // yo*2 rows of 2KB
  const short8* pBbase = (const short8*)wt2 + half * 32 + l31;

  f32x16 acc[2][2] = {};

  #pragma unroll
  for (int k = 0; k < 12; ++k)
    async_copy16(smem + (k * 256 + tid) * 16, gsrc + gbase[k]);
  __syncthreads();

  for (int co8 = 0; co8 < 8; ++co8) {
    #pragma unroll
    for (int dx = 0; dx < 3; ++dx) {
      bool v = vA[dx];
      int o = offA[dx] + ybase;
      short8 A[4][4];
      #pragma unroll
      for (int zs = 0; zs < 4; ++zs)
        #pragma unroll
        for (int yr = 0; yr < 4; ++yr) {
          short8 a = *(const short8*)(smem + (zs * 12288 + yr * 2048) + o);
          A[zs][yr] = v ? a : zer;
        }
      __builtin_amdgcn_s_setprio(1);
      #pragma unroll
      for (int dz = 0; dz < 3; ++dz) {
        #pragma unroll
        for (int dy = 0; dy < 3; ++dy) {
          short8 bf = pBbase[((co8 * 9 + dy * 3 + dx) * 3 + dz) * 64];
          acc[0][0] = __builtin_amdgcn_mfma_f32_32x32x16_bf16(A[dz + 0][dy + 0], bf, acc[0][0], 0, 0, 0);
          acc[1][0] = __builtin_amdgcn_mfma_f32_32x32x16_bf16(A[dz + 1][dy + 0], bf, acc[1][0], 0, 0, 0);
          acc[0][1] = __builtin_amdgcn_mfma_f32_32x32x16_bf16(A[dz + 0][dy + 1], bf, acc[0][1], 0, 0, 0);
          acc[1][1] = __builtin_amdgcn_mfma_f32_32x32x16_bf16(A[dz + 1][dy + 1], bf, acc[1][1], 0, 0, 0);
        }
      }
      __builtin_amdgcn_s_setprio(0);
    }
    __syncthreads();                               // all reads of window done
    if (co8 < 7) {
      int cadd = (co8 + 1) * 2048;
      #pragma unroll
      for (int k = 0; k < 12; ++k)
        async_copy16(smem + (k * 256 + tid) * 16,
                     gsrc + gbase[k] + (cadd & gmask[k]));
      __syncthreads();                             // drains vmcnt -> window ready
    }
  }

  float b1v = c1b[l31];
  float w2v = c2w[l31];
  float b2v = c2b[0];
  int cnt0 = 0, cnt1 = 0;
  #pragma unroll
  for (int zi = 0; zi < 2; ++zi) {
    #pragma unroll
    for (int yi = 0; yi < 2; ++yi) {
      #pragma unroll
      for (int r = 0; r < 16; ++r) {
        float v = fmaxf(acc[zi][yi][r] + b1v, 0.f) * w2v;
        v += __shfl_xor(v, 1);
        v += __shfl_xor(v, 2);
        v += __shfl_xor(v, 4);
        v += __shfl_xor(v, 8);
        v += __shfl_xor(v, 16);
        int bit = (v + b2v) > THR_LOGIT;
        if (r < 8) cnt0 += bit; else cnt1 += bit; // xp-local = (row>=16) = (r>=8)
      }
    }
  }
  if (l31 == 0) {                                  // lanes 0 and 32: disjoint row sets
    atomicAdd(&lcnt[xh * 2 + 0], cnt0);
    atomicAdd(&lcnt[xh * 2 + 1], cnt1);
  }
  __syncthreads();
  if (tid < 4) {
    int n = (zb >> 3) * 16 + (yg >> 2) * 4 + tid;
    atomicAdd(&counts[b * 64 + n], lcnt[tid]);
  }
}

// ---------------- reduce S4 -> X vec rows (deterministic) ----------------
__global__ void __launch_bounds__(256) k_vecreduce(const float* __restrict__ S4a,
    const float* __restrict__ S4p, float* __restrict__ Xmat) {
  int g = blockIdx.x * 256 + threadIdx.x;   // 32768
  int ten = g >> 14, rem = g & 16383;
  int b = rem >> 13, n = (rem >> 7) & 63, c = rem & 127;
  int zp = n >> 4, yp = (n >> 2) & 3, xp = n & 3;
  const float* S = ten ? S4p : S4a;
  float s = 0.f;
  #pragma unroll
  for (int k = 0; k < 16; ++k)
    s += S[((long)(b * 64 + zp * 16 + k) * 4 + yp) * 512 + c * 4 + xp];
  Xmat[(long)(ten * 128 + b * 64 + n) * 128 + c] = s * (1.f / 4096.f);
}

// ---------------- projector MLP + normalize ----------------
__global__ void __launch_bounds__(256) k_proj(const float* __restrict__ Xmat,
    const float* __restrict__ w1t, const float* __restrict__ pb1,
    const float* __restrict__ w2t, const float* __restrict__ pb2,
    float* __restrict__ P) {
  __shared__ float xsT[128][20];
  __shared__ float hsT[128][20];
  __shared__ float os[16][68];
  int bi = blockIdx.x;
  long row0 = (long)bi * 16;
  int t = threadIdx.x;
  {
    int r = t >> 4, c0 = (t & 15) * 8;
    const float* xp = Xmat + (row0 + r) * 128 + c0;
    #pragma unroll
    for (int k = 0; k < 8; ++k) xsT[c0 + k][r] = xp[k];
  }
  __syncthreads();
  {
    int j = t & 127, rh = t >> 7;
    float hacc[8];
    float bb = pb1[j];
    #pragma unroll
    for (int r8 = 0; r8 < 8; ++r8) hacc[r8] = bb;
    for (int c = 0; c < 128; ++c) {
      float w = w1t[c * 128 + j];
      float4 xlo = *(const float4*)&xsT[c][rh * 8];
      float4 xhi = *(const float4*)&xsT[c][rh * 8 + 4];
      hacc[0] += xlo.x * w; hacc[1] += xlo.y * w; hacc[2] += xlo.z * w; hacc[3] += xlo.w * w;
      hacc[4] += xhi.x * w; hacc[5] += xhi.y * w; hacc[6] += xhi.z * w; hacc[7] += xhi.w * w;
    }
    #pragma unroll
    for (int r8 = 0; r8 < 8; ++r8) hsT[j][rh * 8 + r8] = fmaxf(hacc[r8], 0.f);
  }
  __syncthreads();
  {
    int d = t & 63, rq = t >> 6;
    float oacc[4];
    float bb = pb2[d];
    #pragma unroll
    for (int r4 = 0; r4 < 4; ++r4) oacc[r4] = bb;
    for (int j = 0; j < 128; ++j) {
      float w = w2t[j * 64 + d];
      float4 hv = *(const float4*)&hsT[j][rq * 4];
      oacc[0] += hv.x * w; oacc[1] += hv.y * w; oacc[2] += hv.z * w; oacc[3] += hv.w * w;
    }
    #pragma unroll
    for (int r4 = 0; r4 < 4; ++r4) os[rq * 4 + r4][d] = oacc[r4];
  }
  __syncthreads();
  {
    int r = t >> 4, dg = t & 15;
    float4 v = *(const float4*)&os[r][dg * 4];
    float ss = v.x * v.x + v.y * v.y + v.z * v.z + v.w * v.w;
    ss += __shfl_xor(ss, 1); ss += __shfl_xor(ss, 2);
    ss += __shfl_xor(ss, 4); ss += __shfl_xor(ss, 8);
    float sc = 1.f / fmaxf(sqrtf(ss), 1e-12f);
    float4 o; o.x = v.x * sc; o.y = v.y * sc; o.z = v.z * sc; o.w = v.w * sc;
    *(float4*)&P[(row0 + r) * 64 + dg * 4] = o;
  }
}

// ---------------- sim + logsumexp per (b,n) ----------------
__global__ void __launch_bounds__(128) k_sim(const float* __restrict__ P,
                                             float* __restrict__ vloss) {
  __shared__ float ps[100][68];
  __shared__ float red[128];
  int bn = blockIdx.x;
  int t = threadIdx.x;
  long pbase = (long)(13056 + bn * 100) * 64;
  for (int i = t; i < 1600; i += 128) {
    int r = i >> 4, dg = i & 15;
    *(float4*)&ps[r][dg * 4] = *(const float4*)&P[pbase + r * 64 + dg * 4];
  }
  float4 areg[16];
  long abase = (long)(256 + bn * 100) * 64;
  if (t < 100) {
    #pragma unroll
    for (int j = 0; j < 16; ++j) areg[j] = *(const float4*)&P[abase + (long)t * 64 + j * 4];
  }
  __syncthreads();
  float res = 0.f;
  if (t < 100) {
    float m = -1e30f, sum = 0.f, diag = 0.f;
    for (int t2 = 0; t2 < 100; ++t2) {
      float d = 0.f;
      #pragma unroll
      for (int j = 0; j < 16; ++j) {
        float4 pv = *(const float4*)&ps[t2][j * 4];
        d += areg[j].x * pv.x + areg[j].y * pv.y + areg[j].z * pv.z + areg[j].w * pv.w;
      }
      float sim = d * 10.f;
      if (t2 == t) diag = sim;
      float nm = fmaxf(m, sim);
      sum = sum * __expf(m - nm) + __expf(sim - nm);
      m = nm;
    }
    res = m + logf(sum) - diag;
  }
  red[t] = res;
  __syncthreads();
  if (t == 0) {
    float s = 0.f;
    for (int i = 0; i < 100; ++i) s += red[i];
    vloss[bn] = s * 0.01f;
  }
}

// ---------------- final weighted reduction ----------------
__global__ void __launch_bounds__(128) k_final(const float* __restrict__ P,
    const float* __restrict__ vloss, const int* __restrict__ counts,
    const float* __restrict__ lw, float* __restrict__ out) {
  int t = threadIdx.x;
  int lane = t & 63;
  float pterm = 0.f, vterm = 0.f; int vcnt = 0;
  {
    int c = counts[t];
    bool maskv = c >= 2458;   // ratio > 0.6
    bool maskp = c <= 1638;   // ratio < 0.4
    float d = 0.f;
    for (int k = 0; k < 64; ++k) d += P[t * 64 + k] * P[(128 + t) * 64 + k];
    if (maskp) { pterm = -d * 10.f; vcnt += 1; }
    if (maskv) { vterm = vloss[t];  vcnt += 1; }
  }
  for (int m = 1; m < 64; m <<= 1) {
    pterm += __shfl_xor(pterm, m);
    vterm += __shfl_xor(vterm, m);
    vcnt  += __shfl_xor(vcnt, m);
  }
  __shared__ float sp[2], sv[2]; __shared__ int sc[2];
  if (lane == 0) { sp[t >> 6] = pterm; sv[t >> 6] = vterm; sc[t >> 6] = vcnt; }
  __syncthreads();
  if (t == 0) {
    float psum = sp[0] + sp[1], vsum = sv[0] + sv[1];
    int vc = sc[0] + sc[1];
    float total = lw[0] * psum + lw[1] * vsum;
    out[0] = (vc > 0) ? total / (float)vc : 0.f;
  }
}

// ---------------- launch ----------------
extern "C" void kernel_launch(void* const* d_in, const int* in_sizes, int n_in,
                              void* d_out, int out_size, void* d_ws, size_t ws_size,
                              hipStream_t stream) {
  const float* anchor   = (const float*)d_in[0];
  const float* positive = (const float*)d_in[1];
  const float* c1w = (const float*)d_in[2];
  const float* c1b = (const float*)d_in[3];
  const float* c2w = (const float*)d_in[4];
  const float* c2b = (const float*)d_in[5];
  const float* pw1 = (const float*)d_in[6];
  const float* pb1 = (const float*)d_in[7];
  const float* pw2 = (const float*)d_in[8];
  const float* pb2 = (const float*)d_in[9];
  const float* lw  = (const float*)d_in[10];
  const int*   vidx = (const int*)d_in[11];

  char* ws = (char*)d_ws;
  short* in2   = (short*)(ws + 0);                 // 134,217,728
  float* S4a   = (float*)(ws + 134217728);         // 1,048,576
  float* S4p   = (float*)(ws + 135266304);         // 1,048,576
  float* X     = (float*)(ws + 136314880);         // 13,238,272
  float* P     = (float*)(ws + 149553152);         // 6,619,136
  short* wt2   = (short*)(ws + 156172288);         // 221,184
  float* w1t   = (float*)(ws + 156393472);         // 65,536
  float* w2t   = (float*)(ws + 156459008);         // 32,768
  int*   inv   = (int*)  (ws + 156491776);         // 16,384
  int*   counts= (int*)  (ws + 156508160);         // 512
  float* vloss = (float*)(ws + 156508672);         // 512
  short* zpage = (short*)(ws + ZPAGE_OFF);         // 16,384 (zero page, offset 156509184)

  hipFuncSetAttribute(reinterpret_cast<const void*>(k_fused),
                      hipFuncAttributeMaxDynamicSharedMemorySize, 49152);

  hipMemsetAsync(counts, 0, 128 * sizeof(int), stream);
  hipMemsetAsync(zpage, 0, 16384, stream);
  k_prep<<<528, 256, 0, stream>>>(c1w, pw1, pw2, wt2, w1t, w2t);
  k_inv<<<1, 256, 0, stream>>>(vidx, inv);
  k_stage<<<512, 256, 0, stream>>>(anchor, in2, S4a, X, inv, 256);
  k_fused<<<1536, 256, 49152, stream>>>(in2, wt2, c1b, c2w, c2b, counts,
                                        positive, S4p, X, inv);
  k_vecreduce<<<128, 256, 0, stream>>>(S4a, S4p, X);
  k_proj<<<1616, 256, 0, stream>>>(X, w1t, pb1, w2t, pb2, P);
  k_sim<<<128, 128, 0, stream>>>(P, vloss);
  k_final<<<1, 128, 0, stream>>>(P, vloss, counts, lw, (float*)d_out);
}